// Round 15
// baseline (610.278 us; speedup 1.0000x reference)
//
#include <hip/hip_runtime.h>
#include <stdint.h>

#define B_   2
#define L_   4096
#define D_   2048
#define H_   16
#define DK_  128
#define ND3  6144
#define BL_  8192

typedef __bf16 bf16x8 __attribute__((ext_vector_type(8)));
typedef float  f32x4  __attribute__((ext_vector_type(4)));

__device__ __forceinline__ float bf2f(ushort u){ return __uint_as_float(((unsigned)u)<<16); }
__device__ __forceinline__ ushort f2bf(float f){
  unsigned u = __float_as_uint(f);
  unsigned r = u + 0x7FFFu + ((u>>16)&1u);
  return (ushort)(r>>16);
}
__device__ __forceinline__ f32x4 mfma16(bf16x8 a, bf16x8 b, f32x4 c){
  return __builtin_amdgcn_mfma_f32_16x16x32_bf16(a, b, c, 0, 0, 0);
}

#define BAR_LGKM() do{ __builtin_amdgcn_sched_barrier(0); \
  asm volatile("s_waitcnt lgkmcnt(0)" ::: "memory"); \
  __builtin_amdgcn_s_barrier(); \
  __builtin_amdgcn_sched_barrier(0);}while(0)
#define BAR_VMALL() do{ __builtin_amdgcn_sched_barrier(0); \
  asm volatile("s_waitcnt vmcnt(0) lgkmcnt(0)" ::: "memory"); \
  __builtin_amdgcn_s_barrier(); \
  __builtin_amdgcn_sched_barrier(0);}while(0)

__global__ __launch_bounds__(256) void k_cast(const float* __restrict__ x, ushort* __restrict__ y, int n4){
  int i = blockIdx.x*blockDim.x + threadIdx.x;
  int stride = gridDim.x*blockDim.x;
  for (; i < n4; i += stride){
    float4 v = ((const float4*)x)[i];
    ushort4 o; o.x=f2bf(v.x); o.y=f2bf(v.y); o.z=f2bf(v.z); o.w=f2bf(v.w);
    ((ushort4*)y)[i] = o;
  }
}

__global__ __launch_bounds__(256) void k_transpose_cast(const float* __restrict__ in, ushort* __restrict__ out,
                                                        int R, int C){
  __shared__ float tile[32][33];
  int c0 = blockIdx.x*32, r0 = blockIdx.y*32;
  int tx = threadIdx.x, ty = threadIdx.y;
  #pragma unroll
  for (int i=0;i<32;i+=8) tile[ty+i][tx] = in[(size_t)(r0+ty+i)*C + (c0+tx)];
  __syncthreads();
  #pragma unroll
  for (int i=0;i<32;i+=8) out[(size_t)(c0+ty+i)*R + (r0+tx)] = f2bf(tile[tx][ty+i]);
}

// ======== 256x256 GEMM (round-14 kernel, at the measured ~11.4 B/cyc/CU staging ceiling) ========
template<int OUT_BF16>
__global__ __launch_bounds__(512, 1) void k_gemm8(const ushort* __restrict__ A, const ushort* __restrict__ Bt,
                                                  void* __restrict__ Cv, int M, int N, int K){
  __shared__ ushort LDSB[65536];   // 128 KB = 2 bufs x (A 32K | B 32K)
  char* lds = (char*)LDSB;
  const int tid = threadIdx.x, lane = tid & 63, w = tid >> 6;
  const int wm = w >> 2, wn = w & 3;
  int nwg = gridDim.x*gridDim.y;
  int id  = blockIdx.y*gridDim.x + blockIdx.x;
  int sw  = ((nwg & 7) == 0) ? ((id & 7)*(nwg >> 3) + (id >> 3)) : id;
  const int bx = sw % gridDim.x, by = sw / gridDim.x;
  const int m0 = by*256, n0 = bx*256;
  const int NT = K >> 6;
  const size_t rowb = (size_t)K*2;
  const char* gA = (const char*)A  + (size_t)m0*rowb;
  const char* gB = (const char*)Bt + (size_t)n0*rowb;

  f32x4 acc[8][4];
  #pragma unroll
  for (int i=0;i<8;i++)
    #pragma unroll
    for (int j=0;j<4;j++) acc[i][j] = (f32x4){0.f,0.f,0.f,0.f};

  auto stage = [&](int d2, int which, int T){
    const int isB = which >> 1, h = which & 1;
    const char* g = isB ? gB : gA;
    char* halfbase = lds + d2*65536 + isB*32768 + h*16384;
    #pragma unroll
    for (int uu=0; uu<2; ++uu){
      int u = tid + uu*512;
      int band = u >> 7, kk = (u >> 6) & 1, lr = u & 15, lk = (u >> 4) & 3;
      const char* src = g + (size_t)(h*128 + band*16 + lr)*rowb + (size_t)T*128 + kk*64 + lk*16;
      __builtin_amdgcn_global_load_lds(
        (const __attribute__((address_space(1))) void*)src,
        (__attribute__((address_space(3))) void*)(halfbase + u*16), 16, 0, 0);
    }
  };

  stage(0, 0, 0); stage(0, 1, 0); stage(0, 2, 0); stage(0, 3, 0);
  {
    int t1 = (1 < NT) ? 1 : 0;
    stage(1, 0, t1); stage(1, 3, t1);
  }
  asm volatile("s_waitcnt vmcnt(4)" ::: "memory");
  __builtin_amdgcn_s_barrier();

  for (int t = 0; t < NT; ++t){
    const int d = t & 1;
    const char* bufb = lds + d*65536;
    const int tn1 = (t+1 < NT) ? t+1 : NT-1;
    const int tn2 = (t+2 < NT) ? t+2 : NT-1;

    bf16x8 afr[4][2];
    bf16x8 b0r[2][2], b1r[2][2];

    // p1: quadrant (0,0) — read A0 + B0; stage A1(t+1)->otherbuf
    #pragma unroll
    for (int il=0; il<4; ++il)
      #pragma unroll
      for (int kk=0; kk<2; ++kk)
        afr[il][kk] = *(const bf16x8*)(bufb + ((wm*4+il)*2+kk)*1024 + lane*16);
    #pragma unroll
    for (int jl=0; jl<2; ++jl)
      #pragma unroll
      for (int kk=0; kk<2; ++kk)
        b0r[jl][kk] = *(const bf16x8*)(bufb + 32768 + ((wn*2+jl)*2+kk)*1024 + lane*16);
    stage(d^1, 1, tn1);
    __builtin_amdgcn_s_barrier();
    __builtin_amdgcn_s_setprio(1);
    #pragma unroll
    for (int kk=0; kk<2; ++kk)
      #pragma unroll
      for (int il=0; il<4; ++il)
        #pragma unroll
        for (int jl=0; jl<2; ++jl)
          acc[il][jl] = mfma16(afr[il][kk], b0r[jl][kk], acc[il][jl]);
    __builtin_amdgcn_s_setprio(0);
    __builtin_amdgcn_s_barrier();

    // p2: quadrant (0,1) — read B1 (reuse A0); stage B0(t+1)->otherbuf
    #pragma unroll
    for (int jl=0; jl<2; ++jl)
      #pragma unroll
      for (int kk=0; kk<2; ++kk)
        b1r[jl][kk] = *(const bf16x8*)(bufb + 32768 + 16384 + ((wn*2+jl)*2+kk)*1024 + lane*16);
    stage(d^1, 2, tn1);
    __builtin_amdgcn_s_barrier();
    __builtin_amdgcn_s_setprio(1);
    #pragma unroll
    for (int kk=0; kk<2; ++kk)
      #pragma unroll
      for (int il=0; il<4; ++il)
        #pragma unroll
        for (int jl=0; jl<2; ++jl)
          acc[il][2+jl] = mfma16(afr[il][kk], b1r[jl][kk], acc[il][2+jl]);
    __builtin_amdgcn_s_setprio(0);
    __builtin_amdgcn_s_barrier();

    // p3: quadrant (1,1) — read A1 (reuse B1); stage A0(t+2)->samebuf
    #pragma unroll
    for (int il=0; il<4; ++il)
      #pragma unroll
      for (int kk=0; kk<2; ++kk)
        afr[il][kk] = *(const bf16x8*)(bufb + 16384 + ((wm*4+il)*2+kk)*1024 + lane*16);
    stage(d, 0, tn2);
    __builtin_amdgcn_s_barrier();
    __builtin_amdgcn_s_setprio(1);
    #pragma unroll
    for (int kk=0; kk<2; ++kk)
      #pragma unroll
      for (int il=0; il<4; ++il)
        #pragma unroll
        for (int jl=0; jl<2; ++jl)
          acc[4+il][2+jl] = mfma16(afr[il][kk], b1r[jl][kk], acc[4+il][2+jl]);
    __builtin_amdgcn_s_setprio(0);
    __builtin_amdgcn_s_barrier();

    // p4: quadrant (1,0) — no reads (reuse A1 + B0); stage B1(t+2)->samebuf
    stage(d, 3, tn2);
    __builtin_amdgcn_s_barrier();
    __builtin_amdgcn_s_setprio(1);
    #pragma unroll
    for (int kk=0; kk<2; ++kk)
      #pragma unroll
      for (int il=0; il<4; ++il)
        #pragma unroll
        for (int jl=0; jl<2; ++jl)
          acc[4+il][jl] = mfma16(afr[il][kk], b0r[jl][kk], acc[4+il][jl]);
    __builtin_amdgcn_s_setprio(0);
    asm volatile("s_waitcnt vmcnt(4)" ::: "memory");
    __builtin_amdgcn_s_barrier();
  }
  asm volatile("s_waitcnt vmcnt(0) lgkmcnt(0)" ::: "memory");

  #pragma unroll
  for (int fi=0; fi<8; ++fi){
    int row0 = m0 + (fi>>2)*128 + wm*64 + (fi&3)*16 + (lane>>4)*4;
    #pragma unroll
    for (int fj=0; fj<4; ++fj){
      int col = n0 + (fj>>1)*128 + wn*32 + (fj&1)*16 + (lane&15);
      #pragma unroll
      for (int r=0; r<4; ++r){
        float v = acc[fi][fj][r];
        if (OUT_BF16) ((ushort*)Cv)[(size_t)(row0+r)*N + col] = f2bf(v);
        else          ((float*) Cv)[(size_t)(row0+r)*N + col] = v;
      }
    }
  }
}

// ---------------- wbT[h][d] bf16 <- wb[d][h] f32 ----------------
__global__ __launch_bounds__(256) void k_wbt(const float* __restrict__ wb, ushort* __restrict__ wbT){
  int d = blockIdx.x*256 + threadIdx.x;
  #pragma unroll
  for (int h=0;h<16;h++) wbT[(size_t)h*2048 + d] = f2bf(wb[(size_t)d*16 + h]);
}

// ---------------- beta = sigmoid(A16 @ wbT^T) via MFMA; out [b][h][l] f32 ----------------
__global__ __launch_bounds__(64) void k_beta2(const ushort* __restrict__ A16, const ushort* __restrict__ wbT,
                                              float* __restrict__ beta){
  const int rt = blockIdx.x;
  const int lane = threadIdx.x;
  const int lr = lane & 15, lk8 = (lane>>4)*8;
  const int r0 = rt*16;
  f32x4 acc0 = (f32x4){0.f,0.f,0.f,0.f};
  f32x4 acc1 = (f32x4){0.f,0.f,0.f,0.f};
  for (int k0=0; k0<2048; k0+=64){
    bf16x8 a0 = *(const bf16x8*)&A16[(size_t)(r0+lr)*2048 + k0 + lk8];
    bf16x8 b0 = *(const bf16x8*)&wbT[(size_t)lr*2048 + k0 + lk8];
    bf16x8 a1 = *(const bf16x8*)&A16[(size_t)(r0+lr)*2048 + k0 + 32 + lk8];
    bf16x8 b1 = *(const bf16x8*)&wbT[(size_t)lr*2048 + k0 + 32 + lk8];
    acc0 = mfma16(a0, b0, acc0);
    acc1 = mfma16(a1, b1, acc1);
  }
  const int h = lane & 15;
  const int rbase = r0 + (lane>>4)*4;
  #pragma unroll
  for (int r=0;r<4;r++){
    int row = rbase + r;
    int b = row >> 12, l = row & 4095;
    float sg = 1.f/(1.f + __expf(-(acc0[r] + acc1[r])));
    beta[((size_t)(b*H_ + h))*L_ + l] = sg;
  }
}

// ---------------- conv(K=4, causal)+SiLU+heads+l2norm, sliding window ----------------
__global__ __launch_bounds__(256) void k_conv2(const ushort* __restrict__ qkv,
      const float* __restrict__ wq, const float* __restrict__ wk, const float* __restrict__ wv,
      ushort* __restrict__ QH, ushort* __restrict__ KH, ushort* __restrict__ VH){
  const int seg = blockIdx.x, part = blockIdx.y, b = blockIdx.z;
  const int t = threadIdx.x;
  const int ch = t*8;
  const int h = t >> 4, d0 = (t & 15)*8;
  const float* wc = (part==0) ? wq : (part==1) ? wk : wv;
  ushort* outs = ((part==0) ? QH : (part==1) ? KH : VH)
                 + ((size_t)(b*H_ + h)*L_)*DK_ + d0;
  const ushort* inp = qkv + ((size_t)b*L_)*ND3 + part*D_ + ch;

  float wgt[4][8];
  #pragma unroll
  for (int j=0;j<8;j++){
    float4 w4 = *(const float4*)&wc[(ch + j)*4];
    wgt[0][j]=w4.x; wgt[1][j]=w4.y; wgt[2][j]=w4.z; wgt[3][j]=w4.w;
  }

  const int l0 = seg*32;
  float x0[8], x1[8], x2[8];
  {
    float* dsts[3] = {x0, x1, x2};
    #pragma unroll
    for (int i=0;i<3;i++){
      int l = l0 - 3 + i;
      float* d = dsts[i];
      if (l >= 0){
        const ushort* p = inp + (size_t)l*ND3;
        ushort4 a = *(const ushort4*)p, c = *(const ushort4*)(p+4);
        d[0]=bf2f(a.x); d[1]=bf2f(a.y); d[2]=bf2f(a.z); d[3]=bf2f(a.w);
        d[4]=bf2f(c.x); d[5]=bf2f(c.y); d[6]=bf2f(c.z); d[7]=bf2f(c.w);
      } else {
        #pragma unroll
        for (int j=0;j<8;j++) d[j] = 0.f;
      }
    }
  }

  for (int i=0;i<32;i++){
    const int l = l0 + i;
    float cur[8];
    {
      const ushort* p = inp + (size_t)l*ND3;
      ushort4 a = *(const ushort4*)p, c = *(const ushort4*)(p+4);
      cur[0]=bf2f(a.x); cur[1]=bf2f(a.y); cur[2]=bf2f(a.z); cur[3]=bf2f(a.w);
      cur[4]=bf2f(c.x); cur[5]=bf2f(c.y); cur[6]=bf2f(c.z); cur[7]=bf2f(c.w);
    }
    float y[8]; float ss = 0.f;
    #pragma unroll
    for (int j=0;j<8;j++){
      float yy = x0[j]*wgt[0][j] + x1[j]*wgt[1][j] + x2[j]*wgt[2][j] + cur[j]*wgt[3][j];
      yy = yy / (1.f + __expf(-yy));
      y[j] = yy; ss += yy*yy;
    }
    if (part < 2){
      #pragma unroll
      for (int m=1;m<16;m<<=1) ss += __shfl_xor(ss, m, 64);
      float sc = rsqrtf(ss + 1e-12f);
      #pragma unroll
      for (int j=0;j<8;j++) y[j] *= sc;
    }
    ushort4 o0, o1;
    o0.x=f2bf(y[0]); o0.y=f2bf(y[1]); o0.z=f2bf(y[2]); o0.w=f2bf(y[3]);
    o1.x=f2bf(y[4]); o1.y=f2bf(y[5]); o1.z=f2bf(y[6]); o1.w=f2bf(y[7]);
    ushort* op = outs + (size_t)l*DK_;
    *(ushort4*)op = o0; *(ushort4*)(op+4) = o1;
    #pragma unroll
    for (int j=0;j<8;j++){ x0[j]=x1[j]; x1[j]=x2[j]; x2[j]=cur[j]; }
  }
}

// ------- phase 1 v3: per-chunk Tb ONLY (register solve). No Q read, no MM/KT writes. -------
__global__ __launch_bounds__(64) void k_prep(const ushort* __restrict__ KH,
      const float* __restrict__ BETA, ushort* __restrict__ TB){
  const int bid = blockIdx.x, bh = bid>>6, c = bid&63;
  const int lane = threadIdx.x;
  __shared__ ushort Ks[64][136];
  __shared__ float As[64][64];
  __shared__ float bs[64];

  const ushort* kg = KH + ((size_t)bh*L_ + c*64)*DK_;
  {
    const uint4* ks4 = (const uint4*)(kg + (size_t)lane*DK_);
    uint4* kd = (uint4*)&Ks[lane][0];
    #pragma unroll
    for (int i=0;i<16;i++) kd[i] = ks4[i];
    bs[lane] = BETA[(size_t)bh*L_ + c*64 + lane];
  }
  __syncthreads();
  const int lr = lane&15, lk = lane>>4;

  f32x4 gac[4][4];
  #pragma unroll
  for (int i=0;i<4;i++)
    #pragma unroll
    for (int j=0;j<4;j++) gac[i][j] = (f32x4){0.f,0.f,0.f,0.f};
  #pragma unroll
  for (int kk=0;kk<4;kk++){
    bf16x8 fr[4];
    #pragma unroll
    for (int i=0;i<4;i++) fr[i] = *(const bf16x8*)&Ks[i*16+lr][kk*32 + lk*8];
    #pragma unroll
    for (int mi=0;mi<4;mi++)
      #pragma unroll
      for (int ni=0;ni<4;ni++)
        gac[mi][ni] = mfma16(fr[mi], fr[ni], gac[mi][ni]);
  }
  #pragma unroll
  for (int mi=0;mi<4;mi++)
    #pragma unroll
    for (int ni=0;ni<4;ni++)
      #pragma unroll
      for (int r=0;r<4;r++){
        int t = mi*16 + lk*4 + r, s = ni*16 + lr;
        As[t][s] = (s < t) ? (bs[t] * gac[mi][ni][r]) : 0.f;
      }
  __syncthreads();

  float rT[64];
  #pragma unroll
  for (int t=0;t<64;t++){
    float arow = As[t][lane];
    float a = (t==lane) ? 1.f : 0.f;
    #pragma unroll
    for (int s=0;s<t;s++){
      float cc = __int_as_float(__builtin_amdgcn_readlane(__float_as_int(arow), s));
      a -= cc * rT[s];
    }
    rT[t] = a;
  }
  {
    float bc = bs[lane];
    #pragma unroll
    for (int t=0;t<64;t++)
      TB[(size_t)bid*4096 + t*64 + lane] = f2bf(rT[t] * bc);
  }
}

template<int LRB, int GRB, int NB, int XM>
__device__ __forceinline__ void stage_swz(const ushort* __restrict__ g, ushort* l,
                                          int colOff, int w, int lane){
  for (int idx = w; idx < NB/1024; idx += 4){
    int off = idx*1024 + lane*16;
    int row = off / LRB;
    int inner = off & (LRB-1);
    int src = row*GRB + colOff + (inner ^ ((row&XM)<<4));
    __builtin_amdgcn_global_load_lds(
      (const __attribute__((address_space(1))) void*)((const char*)g + src),
      (__attribute__((address_space(3))) void*)((char*)l + idx*1024), 16, 0, 0);
  }
}

// ======= chunk recurrence v4: stage only K,Q,Tb,V (42 KB/chunk); recompute M + Kt in-LDS =======
// 256 blocks (bh x dv-eighth), 256 thr (4 waves). M = tril(Q K^T) recomputed via MFMA with the
// SAME fragment/accumulation order k_prep used (bitwise-identical values); Kt transposed from
// the staged Kc. Both written to single-buffered scratch BEFORE B1 of each chunk; prior-chunk
// reads sealed by the end-of-chunk BAR_VMALL. Staged bytes/chunk 66->42 KB (the measured
// ~11.4 B/cyc/CU staging rate is the kernel's binding constraint).
__global__ __launch_bounds__(256) void k_chunkrec(const ushort* __restrict__ QH, const ushort* __restrict__ KH,
      const ushort* __restrict__ VH, const ushort* __restrict__ TB, ushort* __restrict__ OH){
  const int p = blockIdx.x;
  const int xg = p & 7, s = p >> 3;
  const int bh = xg + (s >> 3)*8;
  const int vo = s & 7;
  const int tid = threadIdx.x, lane = tid&63, w = tid>>6;
  const int lr = lane&15, lk = lane>>4;
  const int tw = w*16;                // t-strip
  const int dw = w*32;                // d-quarter (S-update)

  __shared__ ushort SM[59392];        // 118,784 B
  // panel (dbuf, 21504 ushorts each): Kc@0 Qc@8192 Tbc@16384 Vc@20480
  ushort* Stl = SM + 43008;           // [32? ->] [16..63 rows x128] 2048 ush (4KB)
  ushort* Ztl = SM + 45056;           // 1024 ush
  ushort* Utl = SM + 46080;           // 1024 ush
  ushort* Mc  = SM + 47104;           // [64][64] 4096 ush (8KB)
  ushort* Ktc = SM + 51200;           // [128][64] 8192 ush (16KB)

  const ushort* kbase  = KH + ((size_t)bh*L_)*DK_;
  const ushort* qbase  = QH + ((size_t)bh*L_)*DK_;
  const ushort* vbase  = VH + ((size_t)bh*L_)*DK_;
  const ushort* tbase  = TB + ((size_t)bh*64)*4096;
  ushort* obase = OH + ((size_t)bh*L_)*DK_ + vo*16;

  auto stageall = [&](ushort* buf, int c){
    stage_swz<256,256,16384,7>(kbase + (size_t)c*8192, buf,         0,     w, lane);
    stage_swz<256,256,16384,7>(qbase + (size_t)c*8192, buf + 8192,  0,     w, lane);
    stage_swz<128,128, 8192,7>(tbase + (size_t)c*4096, buf + 16384, 0,     w, lane);
    stage_swz< 32,256, 2048,0>(vbase + (size_t)c*8192, buf + 20480, vo*32, w, lane);
  };

  f32x4 Stf[2];
  Stf[0] = (f32x4){0.f,0.f,0.f,0.f};
  Stf[1] = (f32x4){0.f,0.f,0.f,0.f};

  stageall(SM, 0);
  BAR_VMALL();

  for (int c=0; c<64; ++c){
    ushort* buf  = SM + (c&1)*21504;
    ushort* nbuf = SM + ((c+1)&1)*21504;
    const ushort* Kc  = buf;
    const ushort* Qc  = buf + 8192;
    const ushort* Tbc = buf + 16384;
    const ushort* Vc  = buf + 20480;

    if (c+1 < 64) stageall(nbuf, c+1);

    // --- St (old state) -> LDS ---
    #pragma unroll
    for (int nd=0;nd<2;nd++)
      #pragma unroll
      for (int r=0;r<4;r++){
        int j = lk*4 + r;
        int d = dw + nd*16 + lr;
        Stl[j*128 + (d ^ ((j&7)<<3))] = f2bf(Stf[nd][r]);
      }
    // --- Kt transpose: Ktc[d][t] = Kc[t][d] (pure copy; 16 dword reads + 32 u16 writes/thread) ---
    {
      const int tt = tid & 63, dp0 = tid >> 6;     // dp = d/2
      #pragma unroll
      for (int i=0;i<16;i++){
        int dp = dp0 + 4*i;
        unsigned kk2 = *(const unsigned*)&Kc[tt*128 + ((2*dp) ^ ((tt&7)<<3))];
        Ktc[(2*dp)*64   + (tt ^ (((2*dp)&7)<<3))]   = (ushort)(kk2 & 0xffffu);
        Ktc[(2*dp+1)*64 + (tt ^ (((2*dp+1)&7)<<3))] = (ushort)(kk2 >> 16);
      }
    }
    // --- M = tril_incl(Q K^T), same accumulation order as old k_prep (kk ascending per acc) ---
    {
      f32x4 mac[4];
      #pragma unroll
      for (int ni=0;ni<4;ni++) mac[ni] = (f32x4){0.f,0.f,0.f,0.f};
      #pragma unroll
      for (int kk=0;kk<4;kk++){
        int e = kk*32 + lk*8;
        int ta = tw + lr;
        bf16x8 aq = *(const bf16x8*)&Qc[ta*128 + (e ^ ((ta&7)<<3))];
        #pragma unroll
        for (int ni=0;ni<4;ni++){
          int sr = ni*16 + lr;
          bf16x8 bk = *(const bf16x8*)&Kc[sr*128 + (e ^ ((sr&7)<<3))];
          mac[ni] = mfma16(aq, bk, mac[ni]);
        }
      }
      #pragma unroll
      for (int ni=0;ni<4;ni++)
        #pragma unroll
        for (int r=0;r<4;r++){
          int t = tw + lk*4 + r, sc2 = ni*16 + lr;
          float v = (sc2 <= t) ? mac[ni][r] : 0.f;
          Mc[t*64 + (sc2 ^ ((t&7)<<3))] = f2bf(v);
        }
    }
    BAR_LGKM();                       // B1: Stl, Ktc, Mc visible

    // --- X = K · St^T ---
    f32x4 xac = (f32x4){0.f,0.f,0.f,0.f};
    #pragma unroll
    for (int kk=0;kk<4;kk++){
      int e = kk*32 + lk*8;
      int ta = tw + lr;
      bf16x8 ak  = *(const bf16x8*)&Kc[ta*128 + (e ^ ((ta&7)<<3))];
      bf16x8 bst = *(const bf16x8*)&Stl[lr*128 + (e ^ ((lr&7)<<3))];
      xac = mfma16(ak, bst, xac);
    }
    #pragma unroll
    for (int r=0;r<4;r++){
      int t = tw + lk*4 + r;
      int j = lr;
      float v = bf2f(Vc[t*16 + j]);
      Ztl[j*64 + (t ^ ((j&7)<<3))] = f2bf(v - xac[r]);
    }
    BAR_LGKM();                       // B2

    // --- U = Tb · Z ---
    f32x4 uac = (f32x4){0.f,0.f,0.f,0.f};
    #pragma unroll
    for (int kk=0;kk<2;kk++){
      int e = kk*32 + lk*8;
      int ta = tw + lr;
      bf16x8 at = *(const bf16x8*)&Tbc[ta*64 + (e ^ ((ta&7)<<3))];
      bf16x8 bz = *(const bf16x8*)&Ztl[lr*64 + (e ^ ((lr&7)<<3))];
      uac = mfma16(at, bz, uac);
    }
    #pragma unroll
    for (int r=0;r<4;r++){
      int t = tw + lk*4 + r;
      int j = lr;
      Utl[j*64 + (t ^ ((j&7)<<3))] = f2bf(uac[r]);
    }
    BAR_LGKM();                       // B3

    // --- O = Q·St^T + M·U -> global ---
    f32x4 oac = (f32x4){0.f,0.f,0.f,0.f};
    #pragma unroll
    for (int kk=0;kk<4;kk++){
      int e = kk*32 + lk*8;
      int ta = tw + lr;
      bf16x8 aq  = *(const bf16x8*)&Qc[ta*128 + (e ^ ((ta&7)<<3))];
      bf16x8 bst = *(const bf16x8*)&Stl[lr*128 + (e ^ ((lr&7)<<3))];
      oac = mfma16(aq, bst, oac);
    }
    #pragma unroll
    for (int kk=0;kk<2;kk++){
      int e = kk*32 + lk*8;
      int ta = tw + lr;
      bf16x8 am = *(const bf16x8*)&Mc[ta*64 + (e ^ ((ta&7)<<3))];
      bf16x8 bu = *(const bf16x8*)&Utl[lr*64 + (e ^ ((lr&7)<<3))];
      oac = mfma16(am, bu, oac);
    }
    #pragma unroll
    for (int r=0;r<4;r++){
      int t = tw + lk*4 + r;
      int j = lr;
      obase[(size_t)(c*64 + t)*DK_ + j] = f2bf(oac[r]);
    }

    // --- S-update: Stf += Ut · Kt ---
    #pragma unroll
    for (int kk=0;kk<2;kk++){
      int e = kk*32 + lk*8;
      bf16x8 au = *(const bf16x8*)&Utl[lr*64 + (e ^ ((lr&7)<<3))];
      #pragma unroll
      for (int nd=0;nd<2;nd++){
        int d = dw + nd*16 + lr;
        bf16x8 bk = *(const bf16x8*)&Ktc[d*64 + (e ^ ((d&7)<<3))];
        Stf[nd] = mfma16(au, bk, Stf[nd]);
      }
    }
    BAR_VMALL();                      // end-of-chunk: prefetch landed; all reads of buf done
  }
}

__global__ __launch_bounds__(256) void k_norm(const ushort* __restrict__ OH, const float* __restrict__ gw,
                                              ushort* __restrict__ O2){
  const int blk = blockIdx.x;
  const int b = blk >> 12, l = blk & 4095;
  const int t = threadIdx.x;
  const int h = t >> 4, d0 = (t & 15) * 8;
  const ushort* ip = OH + ((size_t)(b*H_ + h)*L_ + l)*DK_ + d0;
  ushort4 a = *(const ushort4*)ip, c = *(const ushort4*)(ip+4);
  float x[8];
  x[0]=bf2f(a.x); x[1]=bf2f(a.y); x[2]=bf2f(a.z); x[3]=bf2f(a.w);
  x[4]=bf2f(c.x); x[5]=bf2f(c.y); x[6]=bf2f(c.z); x[7]=bf2f(c.w);
  float ss = 0.f;
  #pragma unroll
  for (int j=0;j<8;j++) ss += x[j]*x[j];
  #pragma unroll
  for (int m=1;m<16;m<<=1) ss += __shfl_xor(ss, m, 64);
  float sc = rsqrtf(ss * (1.f/128.f) + 1e-5f);
  ushort* opp = O2 + (size_t)blk*D_ + h*DK_ + d0;
  ushort4 o0, o1;
  o0.x=f2bf(x[0]*sc*gw[d0+0]); o0.y=f2bf(x[1]*sc*gw[d0+1]);
  o0.z=f2bf(x[2]*sc*gw[d0+2]); o0.w=f2bf(x[3]*sc*gw[d0+3]);
  o1.x=f2bf(x[4]*sc*gw[d0+4]); o1.y=f2bf(x[5]*sc*gw[d0+5]);
  o1.z=f2bf(x[6]*sc*gw[d0+6]); o1.w=f2bf(x[7]*sc*gw[d0+7]);
  *(ushort4*)opp = o0; *(ushort4*)(opp+4) = o1;
}

extern "C" void kernel_launch(void* const* d_in, const int* in_sizes, int n_in,
                              void* d_out, int out_size, void* d_ws, size_t ws_size,
                              hipStream_t stream) {
  (void)in_sizes; (void)n_in; (void)out_size; (void)ws_size;
  const float* hidden  = (const float*)d_in[0];
  const float* w_cattn = (const float*)d_in[1];
  const float* wq_conv = (const float*)d_in[2];
  const float* wk_conv = (const float*)d_in[3];
  const float* wv_conv = (const float*)d_in[4];
  const float* w_beta  = (const float*)d_in[5];
  const float* o_nw    = (const float*)d_in[6];
  const float* w_o     = (const float*)d_in[7];
  float* out = (float*)d_out;

  char* W = (char*)d_ws;                              // total 260,046,848 B (known-good size)
  ushort* A16   = (ushort*)(W);                       // 32MB ; -> OH after gemm1
  ushort* WcatT = (ushort*)(W + 33554432u);           // 24MB; dead after gemm1
  ushort* WoT   = (ushort*)(W + 33554432u);           //  8MB (alias, written after gemm1)
  float*  BETA  = (float*) (W + 41943040u);           // 512KB (alias in dead WcatT region)
  ushort* WBT   = (ushort*)(W + 42467328u);           // 64KB  (alias in dead WcatT region)
  ushort* QKV   = (ushort*)(W + 58720256u);           // 96MB; dead after conv
  ushort* TB    = (ushort*)(W + 58720256u);           // 16MB (alias in dead QKV)
  ushort* O2    = (ushort*)(W + 125829120u);          // 32MB
  ushort* QH    = (ushort*)(W + 159383552u);          // 32MB
  ushort* KH    = (ushort*)(W + 192937984u);          // 32MB
  ushort* VH    = (ushort*)(W + 226492416u);          // 32MB -> end 260,046,848
  ushort* OH = A16;

  k_cast<<<4096, 256, 0, stream>>>(hidden, A16, (BL_*D_)/4);
  k_transpose_cast<<<dim3(ND3/32, D_/32), dim3(32,8), 0, stream>>>(w_cattn, WcatT, D_, ND3);
  k_gemm8<1><<<dim3(ND3/256, BL_/256), 512, 0, stream>>>(A16, WcatT, QKV, BL_, ND3, D_);
  // WcatT region dead from here on
  k_transpose_cast<<<dim3(D_/32, D_/32), dim3(32,8), 0, stream>>>(w_o, WoT, D_, D_);
  k_wbt<<<8, 256, 0, stream>>>(w_beta, WBT);
  k_beta2<<<512, 64, 0, stream>>>(A16, WBT, BETA);
  k_conv2<<<dim3(128, 3, 2), 256, 0, stream>>>(QKV, wq_conv, wk_conv, wv_conv, QH, KH, VH);
  k_prep<<<2048, 64, 0, stream>>>(KH, BETA, TB);
  k_chunkrec<<<256, 256, 0, stream>>>(QH, KH, VH, TB, OH);
  k_norm<<<BL_, 256, 0, stream>>>(OH, o_nw, O2);
  k_gemm8<0><<<dim3(D_/256, BL_/256), 512, 0, stream>>>(O2, WoT, out, BL_, D_, D_);
}

// Round 16
// 573.150 us; speedup vs baseline: 1.0648x; 1.0648x over previous
//
#include <hip/hip_runtime.h>
#include <stdint.h>

#define B_   2
#define L_   4096
#define D_   2048
#define H_   16
#define DK_  128
#define ND3  6144
#define BL_  8192

typedef __bf16 bf16x8 __attribute__((ext_vector_type(8)));
typedef float  f32x4  __attribute__((ext_vector_type(4)));

__device__ __forceinline__ float bf2f(ushort u){ return __uint_as_float(((unsigned)u)<<16); }
__device__ __forceinline__ ushort f2bf(float f){
  unsigned u = __float_as_uint(f);
  unsigned r = u + 0x7FFFu + ((u>>16)&1u);
  return (ushort)(r>>16);
}
__device__ __forceinline__ f32x4 mfma16(bf16x8 a, bf16x8 b, f32x4 c){
  return __builtin_amdgcn_mfma_f32_16x16x32_bf16(a, b, c, 0, 0, 0);
}

#define BAR_LGKM() do{ __builtin_amdgcn_sched_barrier(0); \
  asm volatile("s_waitcnt lgkmcnt(0)" ::: "memory"); \
  __builtin_amdgcn_s_barrier(); \
  __builtin_amdgcn_sched_barrier(0);}while(0)
#define BAR_VMALL() do{ __builtin_amdgcn_sched_barrier(0); \
  asm volatile("s_waitcnt vmcnt(0) lgkmcnt(0)" ::: "memory"); \
  __builtin_amdgcn_s_barrier(); \
  __builtin_amdgcn_sched_barrier(0);}while(0)

__global__ __launch_bounds__(256) void k_cast(const float* __restrict__ x, ushort* __restrict__ y, int n4){
  int i = blockIdx.x*blockDim.x + threadIdx.x;
  int stride = gridDim.x*blockDim.x;
  for (; i < n4; i += stride){
    float4 v = ((const float4*)x)[i];
    ushort4 o; o.x=f2bf(v.x); o.y=f2bf(v.y); o.z=f2bf(v.z); o.w=f2bf(v.w);
    ((ushort4*)y)[i] = o;
  }
}

__global__ __launch_bounds__(256) void k_transpose_cast(const float* __restrict__ in, ushort* __restrict__ out,
                                                        int R, int C){
  __shared__ float tile[32][33];
  int c0 = blockIdx.x*32, r0 = blockIdx.y*32;
  int tx = threadIdx.x, ty = threadIdx.y;
  #pragma unroll
  for (int i=0;i<32;i+=8) tile[ty+i][tx] = in[(size_t)(r0+ty+i)*C + (c0+tx)];
  __syncthreads();
  #pragma unroll
  for (int i=0;i<32;i+=8) out[(size_t)(c0+ty+i)*R + (r0+tx)] = f2bf(tile[tx][ty+i]);
}

// ======== 256x256 GEMM, 4-quadrant phases + register reuse (verified best, ~11.4 B/cyc/CU staging ceiling) ========
template<int OUT_BF16>
__global__ __launch_bounds__(512, 1) void k_gemm8(const ushort* __restrict__ A, const ushort* __restrict__ Bt,
                                                  void* __restrict__ Cv, int M, int N, int K){
  __shared__ ushort LDSB[65536];   // 128 KB = 2 bufs x (A 32K | B 32K)
  char* lds = (char*)LDSB;
  const int tid = threadIdx.x, lane = tid & 63, w = tid >> 6;
  const int wm = w >> 2, wn = w & 3;
  int nwg = gridDim.x*gridDim.y;
  int id  = blockIdx.y*gridDim.x + blockIdx.x;
  int sw  = ((nwg & 7) == 0) ? ((id & 7)*(nwg >> 3) + (id >> 3)) : id;
  const int bx = sw % gridDim.x, by = sw / gridDim.x;
  const int m0 = by*256, n0 = bx*256;
  const int NT = K >> 6;
  const size_t rowb = (size_t)K*2;
  const char* gA = (const char*)A  + (size_t)m0*rowb;
  const char* gB = (const char*)Bt + (size_t)n0*rowb;

  f32x4 acc[8][4];
  #pragma unroll
  for (int i=0;i<8;i++)
    #pragma unroll
    for (int j=0;j<4;j++) acc[i][j] = (f32x4){0.f,0.f,0.f,0.f};

  auto stage = [&](int d2, int which, int T){
    const int isB = which >> 1, h = which & 1;
    const char* g = isB ? gB : gA;
    char* halfbase = lds + d2*65536 + isB*32768 + h*16384;
    #pragma unroll
    for (int uu=0; uu<2; ++uu){
      int u = tid + uu*512;
      int band = u >> 7, kk = (u >> 6) & 1, lr = u & 15, lk = (u >> 4) & 3;
      const char* src = g + (size_t)(h*128 + band*16 + lr)*rowb + (size_t)T*128 + kk*64 + lk*16;
      __builtin_amdgcn_global_load_lds(
        (const __attribute__((address_space(1))) void*)src,
        (__attribute__((address_space(3))) void*)(halfbase + u*16), 16, 0, 0);
    }
  };

  stage(0, 0, 0); stage(0, 1, 0); stage(0, 2, 0); stage(0, 3, 0);
  {
    int t1 = (1 < NT) ? 1 : 0;
    stage(1, 0, t1); stage(1, 3, t1);
  }
  asm volatile("s_waitcnt vmcnt(4)" ::: "memory");
  __builtin_amdgcn_s_barrier();

  for (int t = 0; t < NT; ++t){
    const int d = t & 1;
    const char* bufb = lds + d*65536;
    const int tn1 = (t+1 < NT) ? t+1 : NT-1;
    const int tn2 = (t+2 < NT) ? t+2 : NT-1;

    bf16x8 afr[4][2];
    bf16x8 b0r[2][2], b1r[2][2];

    // p1: quadrant (0,0) — read A0 + B0; stage A1(t+1)->otherbuf
    #pragma unroll
    for (int il=0; il<4; ++il)
      #pragma unroll
      for (int kk=0; kk<2; ++kk)
        afr[il][kk] = *(const bf16x8*)(bufb + ((wm*4+il)*2+kk)*1024 + lane*16);
    #pragma unroll
    for (int jl=0; jl<2; ++jl)
      #pragma unroll
      for (int kk=0; kk<2; ++kk)
        b0r[jl][kk] = *(const bf16x8*)(bufb + 32768 + ((wn*2+jl)*2+kk)*1024 + lane*16);
    stage(d^1, 1, tn1);
    __builtin_amdgcn_s_barrier();
    __builtin_amdgcn_s_setprio(1);
    #pragma unroll
    for (int kk=0; kk<2; ++kk)
      #pragma unroll
      for (int il=0; il<4; ++il)
        #pragma unroll
        for (int jl=0; jl<2; ++jl)
          acc[il][jl] = mfma16(afr[il][kk], b0r[jl][kk], acc[il][jl]);
    __builtin_amdgcn_s_setprio(0);
    __builtin_amdgcn_s_barrier();

    // p2: quadrant (0,1) — read B1 (reuse A0); stage B0(t+1)->otherbuf
    #pragma unroll
    for (int jl=0; jl<2; ++jl)
      #pragma unroll
      for (int kk=0; kk<2; ++kk)
        b1r[jl][kk] = *(const bf16x8*)(bufb + 32768 + 16384 + ((wn*2+jl)*2+kk)*1024 + lane*16);
    stage(d^1, 2, tn1);
    __builtin_amdgcn_s_barrier();
    __builtin_amdgcn_s_setprio(1);
    #pragma unroll
    for (int kk=0; kk<2; ++kk)
      #pragma unroll
      for (int il=0; il<4; ++il)
        #pragma unroll
        for (int jl=0; jl<2; ++jl)
          acc[il][2+jl] = mfma16(afr[il][kk], b1r[jl][kk], acc[il][2+jl]);
    __builtin_amdgcn_s_setprio(0);
    __builtin_amdgcn_s_barrier();

    // p3: quadrant (1,1) — read A1 (reuse B1); stage A0(t+2)->samebuf
    #pragma unroll
    for (int il=0; il<4; ++il)
      #pragma unroll
      for (int kk=0; kk<2; ++kk)
        afr[il][kk] = *(const bf16x8*)(bufb + 16384 + ((wm*4+il)*2+kk)*1024 + lane*16);
    stage(d, 0, tn2);
    __builtin_amdgcn_s_barrier();
    __builtin_amdgcn_s_setprio(1);
    #pragma unroll
    for (int kk=0; kk<2; ++kk)
      #pragma unroll
      for (int il=0; il<4; ++il)
        #pragma unroll
        for (int jl=0; jl<2; ++jl)
          acc[4+il][2+jl] = mfma16(afr[il][kk], b1r[jl][kk], acc[4+il][2+jl]);
    __builtin_amdgcn_s_setprio(0);
    __builtin_amdgcn_s_barrier();

    // p4: quadrant (1,0) — no reads (reuse A1 + B0); stage B1(t+2)->samebuf
    stage(d, 3, tn2);
    __builtin_amdgcn_s_barrier();
    __builtin_amdgcn_s_setprio(1);
    #pragma unroll
    for (int kk=0; kk<2; ++kk)
      #pragma unroll
      for (int il=0; il<4; ++il)
        #pragma unroll
        for (int jl=0; jl<2; ++jl)
          acc[4+il][jl] = mfma16(afr[il][kk], b0r[jl][kk], acc[4+il][jl]);
    __builtin_amdgcn_s_setprio(0);
    asm volatile("s_waitcnt vmcnt(4)" ::: "memory");
    __builtin_amdgcn_s_barrier();
  }
  asm volatile("s_waitcnt vmcnt(0) lgkmcnt(0)" ::: "memory");

  #pragma unroll
  for (int fi=0; fi<8; ++fi){
    int row0 = m0 + (fi>>2)*128 + wm*64 + (fi&3)*16 + (lane>>4)*4;
    #pragma unroll
    for (int fj=0; fj<4; ++fj){
      int col = n0 + (fj>>1)*128 + wn*32 + (fj&1)*16 + (lane&15);
      #pragma unroll
      for (int r=0; r<4; ++r){
        float v = acc[fi][fj][r];
        if (OUT_BF16) ((ushort*)Cv)[(size_t)(row0+r)*N + col] = f2bf(v);
        else          ((float*) Cv)[(size_t)(row0+r)*N + col] = v;
      }
    }
  }
}

// ---------------- wbT[h][d] bf16 <- wb[d][h] f32 ----------------
__global__ __launch_bounds__(256) void k_wbt(const float* __restrict__ wb, ushort* __restrict__ wbT){
  int d = blockIdx.x*256 + threadIdx.x;
  #pragma unroll
  for (int h=0;h<16;h++) wbT[(size_t)h*2048 + d] = f2bf(wb[(size_t)d*16 + h]);
}

// ---------------- beta = sigmoid(A16 @ wbT^T) via MFMA; out [b][h][l] f32 ----------------
__global__ __launch_bounds__(64) void k_beta2(const ushort* __restrict__ A16, const ushort* __restrict__ wbT,
                                              float* __restrict__ beta){
  const int rt = blockIdx.x;
  const int lane = threadIdx.x;
  const int lr = lane & 15, lk8 = (lane>>4)*8;
  const int r0 = rt*16;
  f32x4 acc0 = (f32x4){0.f,0.f,0.f,0.f};
  f32x4 acc1 = (f32x4){0.f,0.f,0.f,0.f};
  for (int k0=0; k0<2048; k0+=64){
    bf16x8 a0 = *(const bf16x8*)&A16[(size_t)(r0+lr)*2048 + k0 + lk8];
    bf16x8 b0 = *(const bf16x8*)&wbT[(size_t)lr*2048 + k0 + lk8];
    bf16x8 a1 = *(const bf16x8*)&A16[(size_t)(r0+lr)*2048 + k0 + 32 + lk8];
    bf16x8 b1 = *(const bf16x8*)&wbT[(size_t)lr*2048 + k0 + 32 + lk8];
    acc0 = mfma16(a0, b0, acc0);
    acc1 = mfma16(a1, b1, acc1);
  }
  const int h = lane & 15;
  const int rbase = r0 + (lane>>4)*4;
  #pragma unroll
  for (int r=0;r<4;r++){
    int row = rbase + r;
    int b = row >> 12, l = row & 4095;
    float sg = 1.f/(1.f + __expf(-(acc0[r] + acc1[r])));
    beta[((size_t)(b*H_ + h))*L_ + l] = sg;
  }
}

// ---------------- conv(K=4, causal)+SiLU+heads+l2norm, sliding window ----------------
__global__ __launch_bounds__(256) void k_conv2(const ushort* __restrict__ qkv,
      const float* __restrict__ wq, const float* __restrict__ wk, const float* __restrict__ wv,
      ushort* __restrict__ QH, ushort* __restrict__ KH, ushort* __restrict__ VH){
  const int seg = blockIdx.x, part = blockIdx.y, b = blockIdx.z;
  const int t = threadIdx.x;
  const int ch = t*8;
  const int h = t >> 4, d0 = (t & 15)*8;
  const float* wc = (part==0) ? wq : (part==1) ? wk : wv;
  ushort* outs = ((part==0) ? QH : (part==1) ? KH : VH)
                 + ((size_t)(b*H_ + h)*L_)*DK_ + d0;
  const ushort* inp = qkv + ((size_t)b*L_)*ND3 + part*D_ + ch;

  float wgt[4][8];
  #pragma unroll
  for (int j=0;j<8;j++){
    float4 w4 = *(const float4*)&wc[(ch + j)*4];
    wgt[0][j]=w4.x; wgt[1][j]=w4.y; wgt[2][j]=w4.z; wgt[3][j]=w4.w;
  }

  const int l0 = seg*32;
  float x0[8], x1[8], x2[8];
  {
    float* dsts[3] = {x0, x1, x2};
    #pragma unroll
    for (int i=0;i<3;i++){
      int l = l0 - 3 + i;
      float* d = dsts[i];
      if (l >= 0){
        const ushort* p = inp + (size_t)l*ND3;
        ushort4 a = *(const ushort4*)p, c = *(const ushort4*)(p+4);
        d[0]=bf2f(a.x); d[1]=bf2f(a.y); d[2]=bf2f(a.z); d[3]=bf2f(a.w);
        d[4]=bf2f(c.x); d[5]=bf2f(c.y); d[6]=bf2f(c.z); d[7]=bf2f(c.w);
      } else {
        #pragma unroll
        for (int j=0;j<8;j++) d[j] = 0.f;
      }
    }
  }

  for (int i=0;i<32;i++){
    const int l = l0 + i;
    float cur[8];
    {
      const ushort* p = inp + (size_t)l*ND3;
      ushort4 a = *(const ushort4*)p, c = *(const ushort4*)(p+4);
      cur[0]=bf2f(a.x); cur[1]=bf2f(a.y); cur[2]=bf2f(a.z); cur[3]=bf2f(a.w);
      cur[4]=bf2f(c.x); cur[5]=bf2f(c.y); cur[6]=bf2f(c.z); cur[7]=bf2f(c.w);
    }
    float y[8]; float ss = 0.f;
    #pragma unroll
    for (int j=0;j<8;j++){
      float yy = x0[j]*wgt[0][j] + x1[j]*wgt[1][j] + x2[j]*wgt[2][j] + cur[j]*wgt[3][j];
      yy = yy / (1.f + __expf(-yy));
      y[j] = yy; ss += yy*yy;
    }
    if (part < 2){
      #pragma unroll
      for (int m=1;m<16;m<<=1) ss += __shfl_xor(ss, m, 64);
      float sc = rsqrtf(ss + 1e-12f);
      #pragma unroll
      for (int j=0;j<8;j++) y[j] *= sc;
    }
    ushort4 o0, o1;
    o0.x=f2bf(y[0]); o0.y=f2bf(y[1]); o0.z=f2bf(y[2]); o0.w=f2bf(y[3]);
    o1.x=f2bf(y[4]); o1.y=f2bf(y[5]); o1.z=f2bf(y[6]); o1.w=f2bf(y[7]);
    ushort* op = outs + (size_t)l*DK_;
    *(ushort4*)op = o0; *(ushort4*)(op+4) = o1;
    #pragma unroll
    for (int j=0;j<8;j++){ x0[j]=x1[j]; x1[j]=x2[j]; x2[j]=cur[j]; }
  }
}

// ---------------- phase 1 v2: per-chunk Tb, M, Kt — register solve, 35KB LDS ----------------
__global__ __launch_bounds__(64) void k_prep(const ushort* __restrict__ QH, const ushort* __restrict__ KH,
      const float* __restrict__ BETA, ushort* __restrict__ TB, ushort* __restrict__ MM,
      ushort* __restrict__ KT){
  const int bid = blockIdx.x, bh = bid>>6, c = bid&63;
  const int lane = threadIdx.x;
  __shared__ ushort Ks[64][136];
  __shared__ __align__(16) char QA[17408];
  __shared__ float bs[64];
  ushort (*Qs)[136] = (ushort (*)[136])QA;
  float  (*As)[64]  = (float  (*)[64])QA;

  const ushort* kg = KH + ((size_t)bh*L_ + c*64)*DK_;
  const ushort* qg = QH + ((size_t)bh*L_ + c*64)*DK_;
  {
    const uint4* ks4 = (const uint4*)(kg + (size_t)lane*DK_);
    const uint4* qs4 = (const uint4*)(qg + (size_t)lane*DK_);
    uint4* kd = (uint4*)&Ks[lane][0];
    uint4* qd = (uint4*)&Qs[lane][0];
    #pragma unroll
    for (int i=0;i<16;i++){ kd[i] = ks4[i]; qd[i] = qs4[i]; }
    bs[lane] = BETA[(size_t)bh*L_ + c*64 + lane];
  }
  __syncthreads();
  const int lr = lane&15, lk = lane>>4;

  f32x4 gac[4][4];
  #pragma unroll
  for (int i=0;i<4;i++)
    #pragma unroll
    for (int j=0;j<4;j++) gac[i][j] = (f32x4){0.f,0.f,0.f,0.f};
  #pragma unroll
  for (int kk=0;kk<4;kk++){
    bf16x8 fr[4];
    #pragma unroll
    for (int i=0;i<4;i++) fr[i] = *(const bf16x8*)&Ks[i*16+lr][kk*32 + lk*8];
    #pragma unroll
    for (int mi=0;mi<4;mi++)
      #pragma unroll
      for (int ni=0;ni<4;ni++)
        gac[mi][ni] = mfma16(fr[mi], fr[ni], gac[mi][ni]);
  }
  {
    f32x4 mac[4][4];
    #pragma unroll
    for (int i=0;i<4;i++)
      #pragma unroll
      for (int j=0;j<4;j++) mac[i][j] = (f32x4){0.f,0.f,0.f,0.f};
    #pragma unroll
    for (int kk=0;kk<4;kk++){
      bf16x8 frq[4], frk[4];
      #pragma unroll
      for (int i=0;i<4;i++){
        frq[i] = *(const bf16x8*)&Qs[i*16+lr][kk*32 + lk*8];
        frk[i] = *(const bf16x8*)&Ks[i*16+lr][kk*32 + lk*8];
      }
      #pragma unroll
      for (int mi=0;mi<4;mi++)
        #pragma unroll
        for (int ni=0;ni<4;ni++)
          mac[mi][ni] = mfma16(frq[mi], frk[ni], mac[mi][ni]);
    }
    #pragma unroll
    for (int mi=0;mi<4;mi++)
      #pragma unroll
      for (int ni=0;ni<4;ni++)
        #pragma unroll
        for (int r=0;r<4;r++){
          int t = mi*16 + lk*4 + r, s = ni*16 + lr;
          float v = (s <= t) ? mac[mi][ni][r] : 0.f;
          MM[(size_t)bid*4096 + t*64 + s] = f2bf(v);
        }
  }
  __syncthreads();

  #pragma unroll
  for (int mi=0;mi<4;mi++)
    #pragma unroll
    for (int ni=0;ni<4;ni++)
      #pragma unroll
      for (int r=0;r<4;r++){
        int t = mi*16 + lk*4 + r, s = ni*16 + lr;
        As[t][s] = (s < t) ? (bs[t] * gac[mi][ni][r]) : 0.f;
      }
  __syncthreads();

  float rT[64];
  #pragma unroll
  for (int t=0;t<64;t++){
    float arow = As[t][lane];
    float a = (t==lane) ? 1.f : 0.f;
    #pragma unroll
    for (int s=0;s<t;s++){
      float cc = __int_as_float(__builtin_amdgcn_readlane(__float_as_int(arow), s));
      a -= cc * rT[s];
    }
    rT[t] = a;
  }
  {
    float bc = bs[lane];
    #pragma unroll
    for (int t=0;t<64;t++)
      TB[(size_t)bid*4096 + t*64 + lane] = f2bf(rT[t] * bc);
  }
  for (int d2=0; d2<64; d2++){
    unsigned uu = *(const unsigned*)&Ks[lane][2*d2];
    KT[(size_t)bid*8192 + (size_t)(2*d2)*64 + lane]   = (ushort)(uu & 0xffffu);
    KT[(size_t)bid*8192 + (size_t)(2*d2+1)*64 + lane] = (ushort)(uu >> 16);
  }
}

template<int LRB, int GRB, int NB, int XM>
__device__ __forceinline__ void stage_swz(const ushort* __restrict__ g, ushort* l,
                                          int colOff, int w, int lane){
  for (int idx = w; idx < NB/1024; idx += 4){
    int off = idx*1024 + lane*16;
    int row = off / LRB;
    int inner = off & (LRB-1);
    int src = row*GRB + colOff + (inner ^ ((row&XM)<<4));
    __builtin_amdgcn_global_load_lds(
      (const __attribute__((address_space(1))) void*)((const char*)g + src),
      (__attribute__((address_space(3))) void*)((char*)l + idx*1024), 16, 0, 0);
  }
}

// ======= chunk recurrence v3: 256 blocks (bh x dv-eighth), dbuf panels, raw barriers =======
__global__ __launch_bounds__(256) void k_chunkrec(const ushort* __restrict__ QH, const ushort* __restrict__ KH,
      const ushort* __restrict__ VH, const ushort* __restrict__ TB, const ushort* __restrict__ MM,
      const ushort* __restrict__ KT, ushort* __restrict__ OH){
  const int p = blockIdx.x;
  const int xg = p & 7, s = p >> 3;
  const int bh = xg + (s >> 3)*8;
  const int vo = s & 7;
  const int tid = threadIdx.x, lane = tid&63, w = tid>>6;
  const int lr = lane&15, lk = lane>>4;
  const int tw = w*16;
  const int dw = w*32;

  __shared__ ushort SM[71680];
  ushort* Stl = SM + 67584;
  ushort* Ztl = SM + 69632;
  ushort* Utl = SM + 70656;

  const ushort* kbase  = KH + ((size_t)bh*L_)*DK_;
  const ushort* qbase  = QH + ((size_t)bh*L_)*DK_;
  const ushort* vbase  = VH + ((size_t)bh*L_)*DK_;
  const ushort* tbase  = TB + ((size_t)bh*64)*4096;
  const ushort* mbase  = MM + ((size_t)bh*64)*4096;
  const ushort* ktbase = KT + ((size_t)bh*64)*8192;
  ushort* obase = OH + ((size_t)bh*L_)*DK_ + vo*16;

  auto stageall = [&](ushort* buf, int c){
    stage_swz<256,256,16384,7>(kbase  + (size_t)c*8192, buf,         0,     w, lane);
    stage_swz<256,256,16384,7>(qbase  + (size_t)c*8192, buf + 8192,  0,     w, lane);
    stage_swz<128,128,16384,7>(ktbase + (size_t)c*8192, buf + 16384, 0,     w, lane);
    stage_swz<128,128, 8192,7>(tbase  + (size_t)c*4096, buf + 24576, 0,     w, lane);
    stage_swz<128,128, 8192,7>(mbase  + (size_t)c*4096, buf + 28672, 0,     w, lane);
    stage_swz< 32,256, 2048,0>(vbase  + (size_t)c*8192, buf + 32768, vo*32, w, lane);
  };

  f32x4 Stf[2];
  Stf[0] = (f32x4){0.f,0.f,0.f,0.f};
  Stf[1] = (f32x4){0.f,0.f,0.f,0.f};

  stageall(SM, 0);
  BAR_VMALL();

  for (int c=0; c<64; ++c){
    ushort* buf  = SM + (c&1)*33792;
    ushort* nbuf = SM + ((c+1)&1)*33792;
    const ushort* Kc  = buf;
    const ushort* Qc  = buf + 8192;
    const ushort* Ktc = buf + 16384;
    const ushort* Tbc = buf + 24576;
    const ushort* Mc  = buf + 28672;
    const ushort* Vc  = buf + 32768;

    if (c+1 < 64) stageall(nbuf, c+1);

    #pragma unroll
    for (int nd=0;nd<2;nd++)
      #pragma unroll
      for (int r=0;r<4;r++){
        int j = lk*4 + r;
        int d = dw + nd*16 + lr;
        Stl[j*128 + (d ^ ((j&7)<<3))] = f2bf(Stf[nd][r]);
      }
    BAR_LGKM();

    f32x4 xac = (f32x4){0.f,0.f,0.f,0.f};
    #pragma unroll
    for (int kk=0;kk<4;kk++){
      int e = kk*32 + lk*8;
      int ta = tw + lr;
      bf16x8 ak  = *(const bf16x8*)&Kc[ta*128 + (e ^ ((ta&7)<<3))];
      bf16x8 bst = *(const bf16x8*)&Stl[lr*128 + (e ^ ((lr&7)<<3))];
      xac = mfma16(ak, bst, xac);
    }
    #pragma unroll
    for (int r=0;r<4;r++){
      int t = tw + lk*4 + r;
      int j = lr;
      float v = bf2f(Vc[t*16 + j]);
      Ztl[j*64 + (t ^ ((j&7)<<3))] = f2bf(v - xac[r]);
    }
    BAR_LGKM();

    f32x4 uac = (f32x4){0.f,0.f,0.f,0.f};
    #pragma unroll
    for (int kk=0;kk<2;kk++){
      int e = kk*32 + lk*8;
      int ta = tw + lr;
      bf16x8 at = *(const bf16x8*)&Tbc[ta*64 + (e ^ ((ta&7)<<3))];
      bf16x8 bz = *(const bf16x8*)&Ztl[lr*64 + (e ^ ((lr&7)<<3))];
      uac = mfma16(at, bz, uac);
    }
    #pragma unroll
    for (int r=0;r<4;r++){
      int t = tw + lk*4 + r;
      int j = lr;
      Utl[j*64 + (t ^ ((j&7)<<3))] = f2bf(uac[r]);
    }
    BAR_LGKM();

    f32x4 oac = (f32x4){0.f,0.f,0.f,0.f};
    #pragma unroll
    for (int kk=0;kk<4;kk++){
      int e = kk*32 + lk*8;
      int ta = tw + lr;
      bf16x8 aq  = *(const bf16x8*)&Qc[ta*128 + (e ^ ((ta&7)<<3))];
      bf16x8 bst = *(const bf16x8*)&Stl[lr*128 + (e ^ ((lr&7)<<3))];
      oac = mfma16(aq, bst, oac);
    }
    #pragma unroll
    for (int kk=0;kk<2;kk++){
      int e = kk*32 + lk*8;
      int ta = tw + lr;
      bf16x8 am = *(const bf16x8*)&Mc[ta*64 + (e ^ ((ta&7)<<3))];
      bf16x8 bu = *(const bf16x8*)&Utl[lr*64 + (e ^ ((lr&7)<<3))];
      oac = mfma16(am, bu, oac);
    }
    #pragma unroll
    for (int r=0;r<4;r++){
      int t = tw + lk*4 + r;
      int j = lr;
      obase[(size_t)(c*64 + t)*DK_ + j] = f2bf(oac[r]);
    }

    #pragma unroll
    for (int kk=0;kk<2;kk++){
      int e = kk*32 + lk*8;
      bf16x8 au = *(const bf16x8*)&Utl[lr*64 + (e ^ ((lr&7)<<3))];
      #pragma unroll
      for (int nd=0;nd<2;nd++){
        int d = dw + nd*16 + lr;
        bf16x8 bk = *(const bf16x8*)&Ktc[d*64 + (e ^ ((d&7)<<3))];
        Stf[nd] = mfma16(au, bk, Stf[nd]);
      }
    }
    BAR_VMALL();
  }
}

__global__ __launch_bounds__(256) void k_norm(const ushort* __restrict__ OH, const float* __restrict__ gw,
                                              ushort* __restrict__ O2){
  const int blk = blockIdx.x;
  const int b = blk >> 12, l = blk & 4095;
  const int t = threadIdx.x;
  const int h = t >> 4, d0 = (t & 15) * 8;
  const ushort* ip = OH + ((size_t)(b*H_ + h)*L_ + l)*DK_ + d0;
  ushort4 a = *(const ushort4*)ip, c = *(const ushort4*)(ip+4);
  float x[8];
  x[0]=bf2f(a.x); x[1]=bf2f(a.y); x[2]=bf2f(a.z); x[3]=bf2f(a.w);
  x[4]=bf2f(c.x); x[5]=bf2f(c.y); x[6]=bf2f(c.z); x[7]=bf2f(c.w);
  float ss = 0.f;
  #pragma unroll
  for (int j=0;j<8;j++) ss += x[j]*x[j];
  #pragma unroll
  for (int m=1;m<16;m<<=1) ss += __shfl_xor(ss, m, 64);
  float sc = rsqrtf(ss * (1.f/128.f) + 1e-5f);
  ushort* opp = O2 + (size_t)blk*D_ + h*DK_ + d0;
  ushort4 o0, o1;
  o0.x=f2bf(x[0]*sc*gw[d0+0]); o0.y=f2bf(x[1]*sc*gw[d0+1]);
  o0.z=f2bf(x[2]*sc*gw[d0+2]); o0.w=f2bf(x[3]*sc*gw[d0+3]);
  o1.x=f2bf(x[4]*sc*gw[d0+4]); o1.y=f2bf(x[5]*sc*gw[d0+5]);
  o1.z=f2bf(x[6]*sc*gw[d0+6]); o1.w=f2bf(x[7]*sc*gw[d0+7]);
  *(ushort4*)opp = o0; *(ushort4*)(opp+4) = o1;
}

extern "C" void kernel_launch(void* const* d_in, const int* in_sizes, int n_in,
                              void* d_out, int out_size, void* d_ws, size_t ws_size,
                              hipStream_t stream) {
  (void)in_sizes; (void)n_in; (void)out_size; (void)ws_size;
  const float* hidden  = (const float*)d_in[0];
  const float* w_cattn = (const float*)d_in[1];
  const float* wq_conv = (const float*)d_in[2];
  const float* wk_conv = (const float*)d_in[3];
  const float* wv_conv = (const float*)d_in[4];
  const float* w_beta  = (const float*)d_in[5];
  const float* o_nw    = (const float*)d_in[6];
  const float* w_o     = (const float*)d_in[7];
  float* out = (float*)d_out;

  char* W = (char*)d_ws;                              // total 260,046,848 B (known-good size)
  ushort* A16   = (ushort*)(W);                       // 32MB ; -> OH after gemm1
  ushort* WcatT = (ushort*)(W + 33554432u);           // 24MB; dead after gemm1
  ushort* WoT   = (ushort*)(W + 33554432u);           //  8MB (alias, written after gemm1)
  float*  BETA  = (float*) (W + 41943040u);           // 512KB (alias in dead WcatT region)
  ushort* WBT   = (ushort*)(W + 42467328u);           // 64KB  (alias in dead WcatT region)
  ushort* QKV   = (ushort*)(W + 58720256u);           // 96MB; dead after conv
  ushort* TB    = (ushort*)(W + 58720256u);           // 16MB (alias in dead QKV)
  ushort* MM    = (ushort*)(W + 75497472u);           // 16MB
  ushort* KT    = (ushort*)(W + 92274688u);           // 32MB
  ushort* O2    = (ushort*)(W + 125829120u);          // 32MB
  ushort* QH    = (ushort*)(W + 159383552u);          // 32MB
  ushort* KH    = (ushort*)(W + 192937984u);          // 32MB
  ushort* VH    = (ushort*)(W + 226492416u);          // 32MB -> end 260,046,848
  ushort* OH = A16;

  k_cast<<<4096, 256, 0, stream>>>(hidden, A16, (BL_*D_)/4);
  k_transpose_cast<<<dim3(ND3/32, D_/32), dim3(32,8), 0, stream>>>(w_cattn, WcatT, D_, ND3);
  k_gemm8<1><<<dim3(ND3/256, BL_/256), 512, 0, stream>>>(A16, WcatT, QKV, BL_, ND3, D_);
  // WcatT region dead from here on
  k_transpose_cast<<<dim3(D_/32, D_/32), dim3(32,8), 0, stream>>>(w_o, WoT, D_, D_);
  k_wbt<<<8, 256, 0, stream>>>(w_beta, WBT);
  k_beta2<<<512, 64, 0, stream>>>(A16, WBT, BETA);
  k_conv2<<<dim3(128, 3, 2), 256, 0, stream>>>(QKV, wq_conv, wk_conv, wv_conv, QH, KH, VH);
  k_prep<<<2048, 64, 0, stream>>>(QH, KH, BETA, TB, MM, KT);
  k_chunkrec<<<256, 256, 0, stream>>>(QH, KH, VH, TB, MM, KT, OH);
  k_norm<<<BL_, 256, 0, stream>>>(OH, o_nw, O2);
  k_gemm8<0><<<dim3(D_/256, BL_/256), 512, 0, stream>>>(O2, WoT, out, BL_, D_, D_);
}